// Round 2
// 1315.857 us; speedup vs baseline: 1.0608x; 1.0608x over previous
//
#include <hip/hip_runtime.h>
#include <math.h>

typedef unsigned short u16;
typedef __bf16 bf16x8 __attribute__((ext_vector_type(8)));
typedef float f32x4 __attribute__((ext_vector_type(4)));

static __device__ __forceinline__ float sigf(float x){ return 1.0f/(1.0f+expf(-x)); }
static __device__ __forceinline__ u16 f2bf(float f){
    unsigned u = __builtin_bit_cast(unsigned, f);
    unsigned r = u + 0x7FFFu + ((u >> 16) & 1u);
    return (u16)(r >> 16);
}
static __device__ __forceinline__ float b2f(u16 s){
    unsigned u = ((unsigned)s) << 16;
    return __builtin_bit_cast(float, u);
}

#define AS1 __attribute__((address_space(1)))
#define AS3 __attribute__((address_space(3)))
// 16B per lane, LDS dest = wave-uniform base + lane*16
static __device__ __forceinline__ void gload16(const void* g, void* l){
    __builtin_amdgcn_global_load_lds((const AS1 void*)g, (AS3 void*)l, 16, 0, 0);
}

// ---------------------------------------------------------------------------
// Weight prep: Wt[n][k] = bf16(W[k][n]), zero-padded to Kpad.
// ---------------------------------------------------------------------------
__global__ void prep_w(const float* __restrict__ W, u16* __restrict__ Wt,
                       int K, int N, int Kpad)
{
    int idx = blockIdx.x * 256 + threadIdx.x;
    if (idx >= N * Kpad) return;
    int n = idx / Kpad, k = idx - n * Kpad;
    Wt[idx] = (k < K) ? f2bf(W[(long)k * N + n]) : (u16)0;
}

// Wt_g[n][k]: k<640 from W_ih[n][k] (already [N][K]), else W_hh[n][k-640]
__global__ void prep_g(const float* __restrict__ W_ih, const float* __restrict__ W_hh,
                       u16* __restrict__ Wt)
{
    int idx = blockIdx.x * 256 + threadIdx.x;   // 1024*896
    int n = idx / 896, k = idx - n * 896;
    float v = (k < 640) ? W_ih[(long)n * 640 + k] : W_hh[(long)n * 256 + (k - 640)];
    Wt[idx] = f2bf(v);
}

// ---------------------------------------------------------------------------
// Generic MFMA GEMM: C = act(A @ Bt^T + bias) * rowscale
//   A: f32 (converted during LDS staging) or bf16, row-major, lda
//   Bt: bf16 [N][Kpad] (pre-transposed weights)
//   tile 128 x BN, BK=32, 256 threads (4 waves), mfma_f32_16x16x32_bf16
//   permA: logical row r -> input row (r&1023)*63 + (r>>10)
// ---------------------------------------------------------------------------
template<bool AF32, int BN>
__launch_bounds__(256)
__global__ void gemm_bf16(const void* __restrict__ Aptr, const u16* __restrict__ Bt,
                          void* __restrict__ Cout, const float* __restrict__ bias,
                          const float* __restrict__ rowscale,
                          int Kreal, int Kpad, int lda, int ldc,
                          int permA, int act, int outBF16)
{
    constexpr int BM = 128, LDT = 40;             // LDS row stride (shorts)
    constexpr int WM = (BN == 128) ? 2 : 4;       // wave grid
    constexpr int MI = BM / WM / 16;              // 4 or 2
    constexpr int NI = 4;
    __shared__ u16 As[BM * LDT];
    __shared__ u16 Bs[BN * LDT];

    const int tid = threadIdx.x;
    const int lane = tid & 63, wv = tid >> 6;
    const int r0 = blockIdx.x * BM, c0 = blockIdx.y * BN;
    const int wr = (wv % WM) * (BM / WM);
    const int wc = (wv / WM) * 64;
    const int l15 = lane & 15, q8 = (lane >> 4) * 8;

    f32x4 acc[MI][NI];
#pragma unroll
    for (int i = 0; i < MI; i++)
#pragma unroll
        for (int j = 0; j < NI; j++) acc[i][j] = (f32x4){0.f, 0.f, 0.f, 0.f};

    for (int kt = 0; kt < Kpad; kt += 32) {
        // ---- stage A tile (128 x 32)
        if (AF32) {
            const float* Ag = (const float*)Aptr;
#pragma unroll
            for (int p = 0; p < 4; p++) {
                int v = tid + p * 256;
                int row = v >> 3, kc = (v & 7) * 4;
                long ar = r0 + row;
                long arow = permA ? ((ar & 1023) * 63 + (ar >> 10)) : ar;
                int k = kt + kc;
                float4 val;
                if (k + 4 <= Kreal) {
                    val = *(const float4*)(Ag + arow * (long)lda + k);
                } else {
                    val.x = (k + 0 < Kreal) ? Ag[arow * (long)lda + k + 0] : 0.f;
                    val.y = (k + 1 < Kreal) ? Ag[arow * (long)lda + k + 1] : 0.f;
                    val.z = (k + 2 < Kreal) ? Ag[arow * (long)lda + k + 2] : 0.f;
                    val.w = (k + 3 < Kreal) ? Ag[arow * (long)lda + k + 3] : 0.f;
                }
                ushort4 o; o.x = f2bf(val.x); o.y = f2bf(val.y); o.z = f2bf(val.z); o.w = f2bf(val.w);
                *(ushort4*)&As[row * LDT + kc] = o;
            }
        } else {
            const u16* Ag = (const u16*)Aptr;
#pragma unroll
            for (int p = 0; p < 2; p++) {
                int v = tid + p * 256;
                int row = v >> 2, kc = (v & 3) * 8;
                long ar = r0 + row;
                *(int4*)&As[row * LDT + kc] = *(const int4*)(Ag + ar * (long)lda + kt + kc);
            }
        }
        // ---- stage B tile (BN x 32), bf16 [N][Kpad]
        constexpr int BCH = BN * 4 / 256;
#pragma unroll
        for (int p = 0; p < BCH; p++) {
            int v = tid + p * 256;
            int row = v >> 2, kc = (v & 3) * 8;
            *(int4*)&Bs[row * LDT + kc] = *(const int4*)(Bt + (long)(c0 + row) * Kpad + kt + kc);
        }
        __syncthreads();

        bf16x8 af[MI], bfr[NI];
#pragma unroll
        for (int mi = 0; mi < MI; mi++)
            af[mi] = *reinterpret_cast<const bf16x8*>(&As[(wr + mi * 16 + l15) * LDT + q8]);
#pragma unroll
        for (int ni = 0; ni < NI; ni++)
            bfr[ni] = *reinterpret_cast<const bf16x8*>(&Bs[(wc + ni * 16 + l15) * LDT + q8]);
#pragma unroll
        for (int mi = 0; mi < MI; mi++)
#pragma unroll
            for (int ni = 0; ni < NI; ni++)
                acc[mi][ni] = __builtin_amdgcn_mfma_f32_16x16x32_bf16(af[mi], bfr[ni], acc[mi][ni], 0, 0, 0);
        __syncthreads();
    }

    // ---- epilogue
#pragma unroll
    for (int mi = 0; mi < MI; mi++) {
#pragma unroll
        for (int ni = 0; ni < NI; ni++) {
#pragma unroll
            for (int r = 0; r < 4; r++) {
                int row = r0 + wr + mi * 16 + (lane >> 4) * 4 + r;
                int col = c0 + wc + ni * 16 + l15;
                float v = acc[mi][ni][r];
                if (bias) v += bias[col];
                if (act == 1) v = tanhf(v);
                if (rowscale) v *= rowscale[(row & 1023) * 63 + (row >> 10)];
                if (outBF16) ((u16*)Cout)[(long)row * ldc + col] = f2bf(v);
                else         ((float*)Cout)[(long)row * ldc + col] = v;
            }
        }
    }
}

// ---------------------------------------------------------------------------
// bf16-A GEMM, m97 structure: global_load_lds (16B) into LINEAR LDS, BK=32.
// tile 128 x 64, 4 waves (each 32 rows x 64 cols), f32 output, no epilogue ops.
// ---------------------------------------------------------------------------
__launch_bounds__(256)
__global__ void gemm_glds64(const u16* __restrict__ A, const u16* __restrict__ Bt,
                            float* __restrict__ Cout, int Kpad, int lda, int ldc)
{
    __shared__ u16 As[128 * 32];
    __shared__ u16 Bs[64 * 32];

    const int tid = threadIdx.x;
    const int lane = tid & 63, wv = tid >> 6;
    const long r0 = (long)blockIdx.x * 128;
    const int wr = wv * 32;
    const int l15 = lane & 15, q8 = (lane >> 4) * 8;
    const int crow = lane >> 2;          // row within 16-row chunk
    const int ckc  = (lane & 3) * 8;     // k offset within row (shorts)

    f32x4 acc[2][4];
#pragma unroll
    for (int i = 0; i < 2; i++)
#pragma unroll
        for (int j = 0; j < 4; j++) acc[i][j] = (f32x4){0.f, 0.f, 0.f, 0.f};

    for (int kt = 0; kt < Kpad; kt += 32) {
        // A: 8 chunks of 1KB (16 rows each); each wave issues 2
#pragma unroll
        for (int i = 0; i < 2; i++) {
            int j = wv * 2 + i;
            int row = j * 16 + crow;
            gload16(A + (r0 + row) * lda + kt + ckc, &As[j * 512]);
        }
        // B: 4 chunks; each wave issues 1
        {
            int row = wv * 16 + crow;
            gload16(Bt + (long)row * Kpad + kt + ckc, &Bs[wv * 512]);
        }
        __syncthreads();   // drains vmcnt(0) before barrier

        bf16x8 af[2], bfr[4];
#pragma unroll
        for (int mi = 0; mi < 2; mi++)
            af[mi] = *reinterpret_cast<const bf16x8*>(&As[(wr + mi * 16 + l15) * 32 + q8]);
#pragma unroll
        for (int ni = 0; ni < 4; ni++)
            bfr[ni] = *reinterpret_cast<const bf16x8*>(&Bs[(ni * 16 + l15) * 32 + q8]);
#pragma unroll
        for (int mi = 0; mi < 2; mi++)
#pragma unroll
            for (int ni = 0; ni < 4; ni++)
                acc[mi][ni] = __builtin_amdgcn_mfma_f32_16x16x32_bf16(af[mi], bfr[ni], acc[mi][ni], 0, 0, 0);
        __syncthreads();
    }

#pragma unroll
    for (int mi = 0; mi < 2; mi++)
#pragma unroll
        for (int ni = 0; ni < 4; ni++)
#pragma unroll
            for (int r = 0; r < 4; r++) {
                long row = r0 + wr + mi * 16 + (lane >> 4) * 4 + r;
                int col = ni * 16 + l15;
                Cout[row * ldc + col] = acc[mi][ni][r];
            }
}

// ---------------------------------------------------------------------------
// Fused gates GEMM + LSTM epilogue, m97-style staging.
// A = concat(xl[.,640] | h0[.,256]) bf16, B = Wt_g [1024][896] bf16.
// Block: 128 rows x 32 cells x 4 gates. Linear LDS [row][32], global_load_lds.
// ---------------------------------------------------------------------------
__launch_bounds__(256)
__global__ void gates_glds(const u16* __restrict__ xl, const u16* __restrict__ h0,
                           const u16* __restrict__ Wt_g,
                           const float* __restrict__ b_ih, const float* __restrict__ b_hh,
                           const float* __restrict__ Cprev,
                           u16* __restrict__ Hbuf, float* __restrict__ Cbuf,
                           int offCur, int offPrev, int Ktot)
{
    __shared__ u16 smem[128 * 136];               // As(4096) + Bs(4096) | Gs(17408)
    __shared__ float bias_s[4][32];
    u16* As = smem;
    u16* Bs = smem + 4096;
    u16* Gs = smem;

    const int tid = threadIdx.x;
    const int lane = tid & 63, wv = tid >> 6;
    const long r0 = (long)blockIdx.x * 128;
    const int by32 = blockIdx.y * 32;
    const int wr = (wv & 1) * 64, wc = (wv >> 1) * 64;
    const int l15 = lane & 15, q8 = (lane >> 4) * 8;
    const int crow = lane >> 2;
    const int ckc  = (lane & 3) * 8;

    if (tid < 128) {
        int g = tid >> 5, c = tid & 31;
        int gcol = g * 256 + by32 + c;
        bias_s[g][c] = b_ih[gcol] + b_hh[gcol];
    }

    f32x4 acc[4][4];
#pragma unroll
    for (int i = 0; i < 4; i++)
#pragma unroll
        for (int j = 0; j < 4; j++) acc[i][j] = (f32x4){0.f, 0.f, 0.f, 0.f};

    for (int kt = 0; kt < Ktot; kt += 32) {
        // A: concat(xl | h0); 8 chunks, 2 per wave. 640%32==0 so no straddle.
#pragma unroll
        for (int i = 0; i < 2; i++) {
            int j = wv * 2 + i;
            int row = j * 16 + crow;
            long ar = r0 + row;
            int k = kt + ckc;
            const u16* src = (kt < 640) ? (xl + ar * 640 + k) : (h0 + ar * 256 + (k - 640));
            gload16(src, &As[j * 512]);
        }
        // B: LDS row j = gate (j>>5)*256 + cell; 8 chunks, 2 per wave
#pragma unroll
        for (int i = 0; i < 2; i++) {
            int j = wv * 2 + i;
            int row = j * 16 + crow;
            long brow = (long)((row >> 5) * 256 + by32 + (row & 31));
            gload16(Wt_g + brow * 896 + kt + ckc, &Bs[j * 512]);
        }
        __syncthreads();

        bf16x8 af[4], bfr[4];
#pragma unroll
        for (int mi = 0; mi < 4; mi++)
            af[mi] = *reinterpret_cast<const bf16x8*>(&As[(wr + mi * 16 + l15) * 32 + q8]);
#pragma unroll
        for (int ni = 0; ni < 4; ni++)
            bfr[ni] = *reinterpret_cast<const bf16x8*>(&Bs[(wc + ni * 16 + l15) * 32 + q8]);
#pragma unroll
        for (int mi = 0; mi < 4; mi++)
#pragma unroll
            for (int ni = 0; ni < 4; ni++)
                acc[mi][ni] = __builtin_amdgcn_mfma_f32_16x16x32_bf16(af[mi], bfr[ni], acc[mi][ni], 0, 0, 0);
        __syncthreads();
    }

    // dump gate tiles to LDS (aliases As/Bs; all reads drained by loop-end barrier)
#pragma unroll
    for (int mi = 0; mi < 4; mi++)
#pragma unroll
        for (int ni = 0; ni < 4; ni++)
#pragma unroll
            for (int r = 0; r < 4; r++) {
                int lr = wr + mi * 16 + (lane >> 4) * 4 + r;
                int lc = wc + ni * 16 + l15;
                Gs[lr * 136 + lc] = f2bf(acc[mi][ni][r]);
            }
    __syncthreads();

    // LSTM combine: 16 (row, cell) pairs per thread
#pragma unroll
    for (int i = 0; i < 16; i++) {
        int r = (tid >> 5) * 16 + i;
        int c = tid & 31;
        float iv = b2f(Gs[r * 136 + c])      + bias_s[0][c];
        float fv = b2f(Gs[r * 136 + 32 + c]) + bias_s[1][c];
        float gv = b2f(Gs[r * 136 + 64 + c]) + bias_s[2][c];
        float ov = b2f(Gs[r * 136 + 96 + c]) + bias_s[3][c];
        long rloc = r0 + r;
        int nd = (int)(rloc >> 10), bb = (int)(rloc & 1023);
        int gcol = by32 + c;
        float c0v = 0.f;
        if (Cprev) {
            long ch = ((long)(offPrev + nd * 2) * 1024 + bb) * 256 + gcol;
            c0v = 0.5f * (Cprev[ch] + Cprev[ch + 262144]);
        }
        float cv = sigf(fv) * c0v + sigf(iv) * tanhf(gv);
        float hv = sigf(ov) * tanhf(cv);
        long orow = ((long)offCur * 1024 + rloc) * 256 + gcol;
        Cbuf[orow] = cv;
        Hbuf[orow] = f2bf(hv);
    }
}

// ---------------------------------------------------------------------------
// Fused attention: logits + softmax + pooling. One block per (i, b).
// Waves compute logits for descendants d = wv, wv+4, ...; 64-lane shuffle
// softmax; then 256-thread pooling over the m descendant H rows.
// ---------------------------------------------------------------------------
__launch_bounds__(256)
__global__ void attn_fused(const float* __restrict__ E, const float* __restrict__ xextall,
                           const float* __restrict__ W_a, const u16* __restrict__ Hbuf,
                           float* __restrict__ pooled, int level, int m, int off)
{
    const int blk = blockIdx.x;            // i*1024 + b
    const int i = blk >> 10, bb = blk & 1023;
    const int tid = threadIdx.x;
    const int ln = tid & 63, wv = tid >> 6;
    __shared__ float xs[64];
    __shared__ float raw[64];
    __shared__ float wsm[64];

    if (tid < 64) xs[tid] = xextall[((long)(off + i) * 1024 + bb) * 64 + tid];
    __syncthreads();

    const float wa = W_a[ln];
    for (int dd = wv; dd < m; dd += 4) {
        // decompose dd -> (source level lp, index q within it)
        int lp = 0, cum = 0;
        for (;;) { int sz = 1 << (level - lp); if (dd < cum + sz) break; cum += sz; lp++; }
        int sz = 1 << (level - lp);
        int q = dd - cum;
        long row = (long)((64 - (64 >> lp)) + i * sz + q) * 1024 + bb;
        float v = tanhf(E[row * 64 + ln] + xs[ln]) * wa;
#pragma unroll
        for (int s = 32; s; s >>= 1) v += __shfl_xor(v, s);
        if (ln == 0) raw[dd] = v;
    }
    __syncthreads();

    if (tid < 64) {
        float v = (tid < m) ? raw[tid] : -1e30f;
        float mx = v;
#pragma unroll
        for (int s = 32; s; s >>= 1) mx = fmaxf(mx, __shfl_xor(mx, s));
        float e = (tid < m) ? expf(v - mx) : 0.f;
        float sum = e;
#pragma unroll
        for (int s = 32; s; s >>= 1) sum += __shfl_xor(sum, s);
        wsm[tid] = e / sum;
    }
    __syncthreads();

    float accv = 0.f;
    int cum = 0;
    for (int lp = 0; lp < level; lp++) {
        int sz = 1 << (level - lp);
        int base = 64 - (64 >> lp);
        for (int q = 0; q < sz; q++) {
            long row = (long)(base + i * sz + q) * 1024 + bb;
            accv = fmaf(wsm[cum + q], b2f(Hbuf[row * 256 + tid]), accv);
        }
        cum += sz;
    }
    pooled[(long)blk * 256 + tid] = accv;
}

// ---------------------------------------------------------------------------
// Output heads. One block per batch b; Hbuf root row is bf16.
// ---------------------------------------------------------------------------
__launch_bounds__(256)
__global__ void heads_kernel(const u16* __restrict__ Hbuf,
                             const float* __restrict__ W_c1, const float* __restrict__ b_c1,
                             const float* __restrict__ W_c2, const float* __restrict__ b_c2,
                             const float* __restrict__ W_c3, const float* __restrict__ b_c3,
                             const float* __restrict__ W_d1, const float* __restrict__ b_d1,
                             const float* __restrict__ W_d2, const float* __restrict__ b_d2,
                             const float* __restrict__ W_d3, const float* __restrict__ b_d3,
                             float* __restrict__ out)
{
    const int bb = blockIdx.x, tid = threadIdx.x;
    __shared__ float root[256];
    __shared__ float t1[128];
    __shared__ float t2[128];
    __shared__ float red[256];
    root[tid] = b2f(Hbuf[((long)62 * 1024 + bb) * 256 + tid]);
    __syncthreads();
    for (int head = 0; head < 2; head++) {
        const float* w1  = head ? W_d1 : W_c1;
        const float* bi1 = head ? b_d1 : b_c1;
        const float* w2  = head ? W_d2 : W_c2;
        const float* bi2 = head ? b_d2 : b_c2;
        const float* w3  = head ? W_d3 : W_c3;
        const float* bi3 = head ? b_d3 : b_c3;
        if (tid < 128) {
            float s = bi1[tid];
            for (int k = 0; k < 256; k++) s = fmaf(root[k], w1[k * 128 + tid], s);
            t1[tid] = fmaxf(s, 0.f);
        }
        __syncthreads();
        if (tid < 128) {
            float s = bi2[tid];
            for (int k = 0; k < 128; k++) s = fmaf(t1[k], w2[k * 128 + tid], s);
            t2[tid] = fmaxf(s, 0.f);
        }
        __syncthreads();
        red[tid] = (tid < 128) ? t2[tid] * w3[tid] : 0.f;
        __syncthreads();
        for (int s = 128; s; s >>= 1) { if (tid < s) red[tid] += red[tid + s]; __syncthreads(); }
        if (tid == 0) out[head * 1024 + bb] = sigf(red[0] + bi3[0]);
        __syncthreads();
    }
}

// ---------------------------------------------------------------------------
extern "C" void kernel_launch(void* const* d_in, const int* in_sizes, int n_in,
                              void* d_out, int out_size, void* d_ws, size_t ws_size,
                              hipStream_t stream)
{
    (void)in_sizes; (void)n_in; (void)out_size;
    const float* op       = (const float*)d_in[0];
    const float* feat     = (const float*)d_in[1];
    const float* cond1    = (const float*)d_in[2];
    const float* cond2    = (const float*)d_in[3];
    const float* bitmap   = (const float*)d_in[4];
    const float* has_cond = (const float*)d_in[5];
    const float* W_op     = (const float*)d_in[6];
    const float* b_op     = (const float*)d_in[7];
    const float* W_feat   = (const float*)d_in[8];
    const float* b_feat   = (const float*)d_in[9];
    const float* W_pred   = (const float*)d_in[10];
    const float* b_pred   = (const float*)d_in[11];
    const float* W_bm     = (const float*)d_in[12];
    const float* b_bm     = (const float*)d_in[13];
    const float* W_ih     = (const float*)d_in[14];
    const float* b_ih     = (const float*)d_in[15];
    const float* W_hh     = (const float*)d_in[16];
    const float* b_hh     = (const float*)d_in[17];
    const float* W_wh     = (const float*)d_in[18];
    const float* W_ext    = (const float*)d_in[19];
    const float* W_a      = (const float*)d_in[20];
    const float* W_ht     = (const float*)d_in[21];
    const float* b_ht     = (const float*)d_in[22];
    const float* W_c1     = (const float*)d_in[23];
    const float* b_c1     = (const float*)d_in[24];
    const float* W_c2     = (const float*)d_in[25];
    const float* b_c2     = (const float*)d_in[26];
    const float* W_c3     = (const float*)d_in[27];
    const float* b_c3     = (const float*)d_in[28];
    const float* W_d1     = (const float*)d_in[29];
    const float* b_d1     = (const float*)d_in[30];
    const float* W_d2     = (const float*)d_in[31];
    const float* b_d2     = (const float*)d_in[32];
    const float* W_d3     = (const float*)d_in[33];
    const float* b_d3     = (const float*)d_in[34];
    float* out = (float*)d_out;

    // workspace layout, node-major rows: row = node_global*1024 + b
    char* p = (char*)d_ws;
    auto alloc = [&](size_t bytes) -> char* {
        char* r = p; p += (bytes + 255) & ~(size_t)255; return r;
    };
    u16*   xall    = (u16*)  alloc((size_t)64512 * 640 * 2);   // bf16 x, all 63 nodes
    float* xextall = (float*)alloc((size_t)64512 * 64 * 4);    // x @ W_ext
    u16*   Hbuf    = (u16*)  alloc((size_t)64512 * 256 * 2);   // hiddens (bf16)
    float* Cbuf    = (float*)alloc((size_t)64512 * 256 * 4);   // cells (f32)
    float* Ebuf    = (float*)alloc((size_t)62 * 1024 * 64 * 4);// H @ W_wh
    float* pooled  = (float*)alloc((size_t)16384 * 256 * 4);
    u16*   h0      = (u16*)  alloc((size_t)16384 * 256 * 2);
    u16*   Wt_op   = (u16*)  alloc((size_t)128 * 32 * 2);
    u16*   Wt_feat = (u16*)  alloc((size_t)128 * 64 * 2);
    u16*   Wt_pred = (u16*)  alloc((size_t)128 * 256 * 2);
    u16*   Wt_bm   = (u16*)  alloc((size_t)128 * 1024 * 2);
    u16*   Wt_g    = (u16*)  alloc((size_t)1024 * 896 * 2);
    u16*   Wt_wh   = (u16*)  alloc((size_t)64 * 256 * 2);
    u16*   Wt_ext  = (u16*)  alloc((size_t)64 * 640 * 2);
    u16*   Wt_ht   = (u16*)  alloc((size_t)256 * 256 * 2);
    if (ws_size < (size_t)(p - (char*)d_ws)) return;

    // ---- weight prep (bf16, [N][K] with K zero-padded to x32)
    prep_w<<<16,  256, 0, stream>>>(W_op,   Wt_op,   32,   128, 32);
    prep_w<<<32,  256, 0, stream>>>(W_feat, Wt_feat, 64,   128, 64);
    prep_w<<<128, 256, 0, stream>>>(W_pred, Wt_pred, 256,  128, 256);
    prep_w<<<512, 256, 0, stream>>>(W_bm,   Wt_bm,   1000, 128, 1024);
    prep_w<<<64,  256, 0, stream>>>(W_wh,   Wt_wh,   256,  64,  256);
    prep_w<<<160, 256, 0, stream>>>(W_ext,  Wt_ext,  640,  64,  640);
    prep_w<<<256, 256, 0, stream>>>(W_ht,   Wt_ht,   256,  256, 256);
    prep_g<<<3584,256, 0, stream>>>(W_ih, W_hh, Wt_g);

    // ---- x projections for ALL 63 nodes at once (M = 64512 = 504*128)
    gemm_bf16<true,128><<<dim3(504,1), 256, 0, stream>>>(op,     Wt_op,   (void*)(xall + 0),   b_op,   nullptr,  32,   32,   32,   640, 1, 0, 1);
    gemm_bf16<true,128><<<dim3(504,1), 256, 0, stream>>>(feat,   Wt_feat, (void*)(xall + 128), b_feat, nullptr,  64,   64,   64,   640, 1, 0, 1);
    gemm_bf16<true,128><<<dim3(504,1), 256, 0, stream>>>(cond1,  Wt_pred, (void*)(xall + 256), b_pred, nullptr,  256,  256,  256,  640, 1, 0, 1);
    gemm_bf16<true,128><<<dim3(504,1), 256, 0, stream>>>(cond2,  Wt_pred, (void*)(xall + 384), b_pred, nullptr,  256,  256,  256,  640, 1, 0, 1);
    gemm_bf16<true,128><<<dim3(504,1), 256, 0, stream>>>(bitmap, Wt_bm,   (void*)(xall + 512), b_bm,   has_cond, 1000, 1024, 1000, 640, 1, 0, 1);
    // xext for all nodes (bf16 A -> m97-style kernel)
    gemm_glds64<<<504, 256, 0, stream>>>(xall, Wt_ext, xextall, 640, 640, 64);

    for (int l = 0; l < 6; l++) {
        const int n   = 32 >> l;
        const int off = 64 - (64 >> l);     // OFFSETS[l] = global node base
        const int M   = n * 1024;
        const int m   = (2 << l) - 2;

        if (l > 0) {
            attn_fused<<<M, 256, 0, stream>>>(Ebuf, xextall, W_a, Hbuf, pooled, l, m, off);
            gemm_bf16<true,128><<<dim3(M/128, 2), 256, 0, stream>>>(pooled, Wt_ht, (void*)h0, b_ht, nullptr, 256, 256, 256, 256, 0, 1, 1);
        }

        const int Ktot    = l ? 896 : 640;
        const int offPrev = l ? (64 - (64 >> (l - 1))) : 0;
        gates_glds<<<dim3(M/128, 8), 256, 0, stream>>>(xall + (size_t)off * 1024 * 640, h0, Wt_g,
                                                       b_ih, b_hh, l ? Cbuf : nullptr,
                                                       Hbuf, Cbuf, off, offPrev, Ktot);

        if (l < 5) {
            gemm_glds64<<<M/128, 256, 0, stream>>>(Hbuf + (size_t)off * 1024 * 256, Wt_wh,
                                                   Ebuf + (size_t)off * 1024 * 64, 256, 256, 64);
        }
    }

    heads_kernel<<<1024, 256, 0, stream>>>(Hbuf, W_c1, b_c1, W_c2, b_c2, W_c3, b_c3,
                                           W_d1, b_d1, W_d2, b_d2, W_d3, b_d3, out);
}

// Round 3
// 1203.170 us; speedup vs baseline: 1.1601x; 1.0937x over previous
//
#include <hip/hip_runtime.h>
#include <math.h>

typedef unsigned short u16;
typedef __bf16 bf16x8 __attribute__((ext_vector_type(8)));
typedef float f32x4 __attribute__((ext_vector_type(4)));

static __device__ __forceinline__ float sigf(float x){ return 1.0f/(1.0f+expf(-x)); }
static __device__ __forceinline__ u16 f2bf(float f){
    unsigned u = __builtin_bit_cast(unsigned, f);
    unsigned r = u + 0x7FFFu + ((u >> 16) & 1u);
    return (u16)(r >> 16);
}
static __device__ __forceinline__ float b2f(u16 s){
    unsigned u = ((unsigned)s) << 16;
    return __builtin_bit_cast(float, u);
}

#define AS1 __attribute__((address_space(1)))
#define AS3 __attribute__((address_space(3)))
// 16B per lane, LDS dest = wave-uniform base + lane*16
static __device__ __forceinline__ void gload16(const void* g, void* l){
    __builtin_amdgcn_global_load_lds((const AS1 void*)g, (AS3 void*)l, 16, 0, 0);
}

// ---------------------------------------------------------------------------
// Weight prep: Wt[n][k] = bf16(W[k][n]), zero-padded to Kpad.
// ---------------------------------------------------------------------------
__global__ void prep_w(const float* __restrict__ W, u16* __restrict__ Wt,
                       int K, int N, int Kpad)
{
    int idx = blockIdx.x * 256 + threadIdx.x;
    if (idx >= N * Kpad) return;
    int n = idx / Kpad, k = idx - n * Kpad;
    Wt[idx] = (k < K) ? f2bf(W[(long)k * N + n]) : (u16)0;
}

// Wt_gi[n'][k], n' = cell*4 + gate (interleaved). Source row = gate*256 + cell.
// k<640 from W_ih, else W_hh.
__global__ void prep_g(const float* __restrict__ W_ih, const float* __restrict__ W_hh,
                       u16* __restrict__ Wt)
{
    int idx = blockIdx.x * 256 + threadIdx.x;   // 1024*896
    int np = idx / 896, k = idx - np * 896;
    int n_old = (np & 3) * 256 + (np >> 2);
    float v = (k < 640) ? W_ih[(long)n_old * 640 + k] : W_hh[(long)n_old * 256 + (k - 640)];
    Wt[idx] = f2bf(v);
}

// ---------------------------------------------------------------------------
// Generic MFMA GEMM (AF32 staging): C = act(A @ Bt^T + bias) * rowscale
//   tile 128 x BN, BK=32, 256 threads (4 waves), mfma_f32_16x16x32_bf16
//   permA: logical row r -> input row (r&1023)*63 + (r>>10)
// ---------------------------------------------------------------------------
template<bool AF32, int BN>
__launch_bounds__(256)
__global__ void gemm_bf16(const void* __restrict__ Aptr, const u16* __restrict__ Bt,
                          void* __restrict__ Cout, const float* __restrict__ bias,
                          const float* __restrict__ rowscale,
                          int Kreal, int Kpad, int lda, int ldc,
                          int permA, int act, int outBF16)
{
    constexpr int BM = 128, LDT = 40;             // LDS row stride (shorts)
    constexpr int WM = (BN == 128) ? 2 : 4;       // wave grid
    constexpr int MI = BM / WM / 16;              // 4 or 2
    constexpr int NI = 4;
    __shared__ u16 As[BM * LDT];
    __shared__ u16 Bs[BN * LDT];

    const int tid = threadIdx.x;
    const int lane = tid & 63, wv = tid >> 6;
    const int r0 = blockIdx.x * BM, c0 = blockIdx.y * BN;
    const int wr = (wv % WM) * (BM / WM);
    const int wc = (wv / WM) * 64;
    const int l15 = lane & 15, q8 = (lane >> 4) * 8;

    f32x4 acc[MI][NI];
#pragma unroll
    for (int i = 0; i < MI; i++)
#pragma unroll
        for (int j = 0; j < NI; j++) acc[i][j] = (f32x4){0.f, 0.f, 0.f, 0.f};

    for (int kt = 0; kt < Kpad; kt += 32) {
        // ---- stage A tile (128 x 32)
        if (AF32) {
            const float* Ag = (const float*)Aptr;
#pragma unroll
            for (int p = 0; p < 4; p++) {
                int v = tid + p * 256;
                int row = v >> 3, kc = (v & 7) * 4;
                long ar = r0 + row;
                long arow = permA ? ((ar & 1023) * 63 + (ar >> 10)) : ar;
                int k = kt + kc;
                float4 val;
                if (k + 4 <= Kreal) {
                    val = *(const float4*)(Ag + arow * (long)lda + k);
                } else {
                    val.x = (k + 0 < Kreal) ? Ag[arow * (long)lda + k + 0] : 0.f;
                    val.y = (k + 1 < Kreal) ? Ag[arow * (long)lda + k + 1] : 0.f;
                    val.z = (k + 2 < Kreal) ? Ag[arow * (long)lda + k + 2] : 0.f;
                    val.w = (k + 3 < Kreal) ? Ag[arow * (long)lda + k + 3] : 0.f;
                }
                ushort4 o; o.x = f2bf(val.x); o.y = f2bf(val.y); o.z = f2bf(val.z); o.w = f2bf(val.w);
                *(ushort4*)&As[row * LDT + kc] = o;
            }
        } else {
            const u16* Ag = (const u16*)Aptr;
#pragma unroll
            for (int p = 0; p < 2; p++) {
                int v = tid + p * 256;
                int row = v >> 2, kc = (v & 3) * 8;
                long ar = r0 + row;
                *(int4*)&As[row * LDT + kc] = *(const int4*)(Ag + ar * (long)lda + kt + kc);
            }
        }
        // ---- stage B tile (BN x 32), bf16 [N][Kpad]
        constexpr int BCH = BN * 4 / 256;
#pragma unroll
        for (int p = 0; p < BCH; p++) {
            int v = tid + p * 256;
            int row = v >> 2, kc = (v & 3) * 8;
            *(int4*)&Bs[row * LDT + kc] = *(const int4*)(Bt + (long)(c0 + row) * Kpad + kt + kc);
        }
        __syncthreads();

        bf16x8 af[MI], bfr[NI];
#pragma unroll
        for (int mi = 0; mi < MI; mi++)
            af[mi] = *reinterpret_cast<const bf16x8*>(&As[(wr + mi * 16 + l15) * LDT + q8]);
#pragma unroll
        for (int ni = 0; ni < NI; ni++)
            bfr[ni] = *reinterpret_cast<const bf16x8*>(&Bs[(wc + ni * 16 + l15) * LDT + q8]);
#pragma unroll
        for (int mi = 0; mi < MI; mi++)
#pragma unroll
            for (int ni = 0; ni < NI; ni++)
                acc[mi][ni] = __builtin_amdgcn_mfma_f32_16x16x32_bf16(af[mi], bfr[ni], acc[mi][ni], 0, 0, 0);
        __syncthreads();
    }

    // ---- epilogue
#pragma unroll
    for (int mi = 0; mi < MI; mi++) {
#pragma unroll
        for (int ni = 0; ni < NI; ni++) {
#pragma unroll
            for (int r = 0; r < 4; r++) {
                int row = r0 + wr + mi * 16 + (lane >> 4) * 4 + r;
                int col = c0 + wc + ni * 16 + l15;
                float v = acc[mi][ni][r];
                if (bias) v += bias[col];
                if (act == 1) v = tanhf(v);
                if (rowscale) v *= rowscale[(row & 1023) * 63 + (row >> 10)];
                if (outBF16) ((u16*)Cout)[(long)row * ldc + col] = f2bf(v);
                else         ((float*)Cout)[(long)row * ldc + col] = v;
            }
        }
    }
}

// ---------------------------------------------------------------------------
// bf16-A GEMM, m97 structure: global_load_lds (16B) into LINEAR LDS, BK=32.
// tile 128 x 64, 4 waves (each 32 rows x 64 cols). Optional bias/tanh/bf16-out,
// optional XCD-aware (bx,by) swizzle when gridDim.y==4 (requires nx % 8 == 0).
// ---------------------------------------------------------------------------
__launch_bounds__(256)
__global__ void gemm_glds64(const u16* __restrict__ A, const u16* __restrict__ Bt,
                            void* __restrict__ Cout, const float* __restrict__ bias,
                            int Kpad, int lda, int ldc, int act, int outBF16, int swz)
{
    __shared__ u16 As[128 * 32];
    __shared__ u16 Bs[64 * 32];

    const int tid = threadIdx.x;
    const int lane = tid & 63, wv = tid >> 6;
    int bx = blockIdx.x, by = blockIdx.y;
    if (swz) {
        int wg = by * gridDim.x + bx;
        int t = wg >> 3;
        bx = (wg & 7) + 8 * (t >> 2);
        by = t & 3;
    }
    const long r0 = (long)bx * 128;
    const int c0 = by * 64;
    const int wr = wv * 32;
    const int l15 = lane & 15, q8 = (lane >> 4) * 8;
    const int crow = lane >> 2;          // row within 16-row chunk
    const int ckc  = (lane & 3) * 8;     // k offset within row (shorts)

    f32x4 acc[2][4];
#pragma unroll
    for (int i = 0; i < 2; i++)
#pragma unroll
        for (int j = 0; j < 4; j++) acc[i][j] = (f32x4){0.f, 0.f, 0.f, 0.f};

    for (int kt = 0; kt < Kpad; kt += 32) {
        // A: 8 chunks of 1KB (16 rows each); each wave issues 2
#pragma unroll
        for (int i = 0; i < 2; i++) {
            int j = wv * 2 + i;
            int row = j * 16 + crow;
            gload16(A + (r0 + row) * lda + kt + ckc, &As[j * 512]);
        }
        // B: 4 chunks; each wave issues 1
        {
            int row = wv * 16 + crow;
            gload16(Bt + (long)(c0 + row) * Kpad + kt + ckc, &Bs[wv * 512]);
        }
        __syncthreads();   // drains vmcnt(0) before barrier

        bf16x8 af[2], bfr[4];
#pragma unroll
        for (int mi = 0; mi < 2; mi++)
            af[mi] = *reinterpret_cast<const bf16x8*>(&As[(wr + mi * 16 + l15) * 32 + q8]);
#pragma unroll
        for (int ni = 0; ni < 4; ni++)
            bfr[ni] = *reinterpret_cast<const bf16x8*>(&Bs[(ni * 16 + l15) * 32 + q8]);
#pragma unroll
        for (int mi = 0; mi < 2; mi++)
#pragma unroll
            for (int ni = 0; ni < 4; ni++)
                acc[mi][ni] = __builtin_amdgcn_mfma_f32_16x16x32_bf16(af[mi], bfr[ni], acc[mi][ni], 0, 0, 0);
        __syncthreads();
    }

#pragma unroll
    for (int mi = 0; mi < 2; mi++)
#pragma unroll
        for (int ni = 0; ni < 4; ni++)
#pragma unroll
            for (int r = 0; r < 4; r++) {
                long row = r0 + wr + mi * 16 + (lane >> 4) * 4 + r;
                int col = c0 + ni * 16 + l15;
                float v = acc[mi][ni][r];
                if (bias) v += bias[col];
                if (act == 1) v = tanhf(v);
                if (outBF16) ((u16*)Cout)[row * ldc + col] = f2bf(v);
                else         ((float*)Cout)[row * ldc + col] = v;
            }
}

// ---------------------------------------------------------------------------
// Fused gates GEMM + LSTM epilogue. BN=256 (64 cells x 4 gates, interleaved
// weights: col j = cell*4 + gate). 512 threads / 8 waves, MI=NI=4, BK=32.
// 1-D grid (M/128)*4, XCD-aware mapping: the 4 cell-tiles of a row-tile run
// consecutively on one XCD so the A panel is an L2 hit.
// Epilogue: 4x4 shuffle transpose within lane quads -> register-only LSTM.
// ---------------------------------------------------------------------------
__launch_bounds__(512, 4)
__global__ void gates_glds(const u16* __restrict__ xl, const u16* __restrict__ h0,
                           const u16* __restrict__ Wt_gi,
                           const float* __restrict__ b_ih, const float* __restrict__ b_hh,
                           const float* __restrict__ Cprev,
                           u16* __restrict__ Hbuf, float* __restrict__ Cbuf,
                           int offCur, int offPrev, int Ktot)
{
    __shared__ u16 As[128 * 32];      // 8 KB
    __shared__ u16 Bs[256 * 32];      // 16 KB
    __shared__ float bias_s[256];

    const int tid = threadIdx.x;
    const int lane = tid & 63, wv = tid >> 6;
    // XCD swizzle: wg -> (row_tile bx, cell_tile by); XCD(wg) assumed wg%8
    {
    }
    int wg = blockIdx.x;
    int t = wg >> 3;
    const int bx = (wg & 7) + 8 * (t >> 2);
    const int by = t & 3;
    const long r0 = (long)bx * 128;
    const int c0cell = by * 64;                    // cell base
    const int wr = (wv & 1) * 64, wc = (wv >> 1) * 64;
    const int l15 = lane & 15, q8 = (lane >> 4) * 8;
    const int crow = lane >> 2;
    const int ckc  = (lane & 3) * 8;

    if (tid < 256) {
        int j = tid;                               // block-local col = cell*4+gate
        int gcol_old = (j & 3) * 256 + c0cell + (j >> 2);
        bias_s[j] = b_ih[gcol_old] + b_hh[gcol_old];
    }

    f32x4 acc[4][4];
#pragma unroll
    for (int i = 0; i < 4; i++)
#pragma unroll
        for (int j = 0; j < 4; j++) acc[i][j] = (f32x4){0.f, 0.f, 0.f, 0.f};

    for (int kt = 0; kt < Ktot; kt += 32) {
        // A: concat(xl | h0); 8 chunks of 16 rows, 1 per wave. No 640-straddle.
        {
            int row = wv * 16 + crow;
            long ar = r0 + row;
            int k = kt + ckc;
            const u16* src = (kt < 640) ? (xl + ar * 640 + k) : (h0 + ar * 256 + (k - 640));
            gload16(src, &As[wv * 512]);
        }
        // B: 16 chunks of 16 rows, 2 per wave; rows = interleaved (cell,gate)
#pragma unroll
        for (int i = 0; i < 2; i++) {
            int j2 = wv * 2 + i;
            int row = j2 * 16 + crow;
            gload16(Wt_gi + (long)(by * 256 + row) * 896 + kt + ckc, &Bs[j2 * 512]);
        }
        __syncthreads();

        bf16x8 af[4], bfr[4];
#pragma unroll
        for (int mi = 0; mi < 4; mi++)
            af[mi] = *reinterpret_cast<const bf16x8*>(&As[(wr + mi * 16 + l15) * 32 + q8]);
#pragma unroll
        for (int ni = 0; ni < 4; ni++)
            bfr[ni] = *reinterpret_cast<const bf16x8*>(&Bs[(wc + ni * 16 + l15) * 32 + q8]);
#pragma unroll
        for (int mi = 0; mi < 4; mi++)
#pragma unroll
            for (int ni = 0; ni < 4; ni++)
                acc[mi][ni] = __builtin_amdgcn_mfma_f32_16x16x32_bf16(af[mi], bfr[ni], acc[mi][ni], 0, 0, 0);
        __syncthreads();
    }

    // ---- register-only LSTM epilogue.
    // Within each lane quad (l15&3 = gate g, rows q*4+r): 4x4 butterfly
    // transpose -> lane p holds all 4 gates of row q*4+p for cell l15>>2.
    const int pq = lane & 1, pq2 = lane & 2;
#pragma unroll
    for (int mi = 0; mi < 4; mi++) {
#pragma unroll
        for (int ni = 0; ni < 4; ni++) {
            float v0 = acc[mi][ni][0], v1 = acc[mi][ni][1];
            float v2 = acc[mi][ni][2], v3 = acc[mi][ni][3];
            // phase 1 (xor 1): swap bit0 of (row-elem, lane)
            float t0 = __shfl_xor(v1, 1);
            float t1 = __shfl_xor(v0, 1);
            float t2 = __shfl_xor(v3, 1);
            float t3 = __shfl_xor(v2, 1);
            float a0 = pq  ? t0 : v0;
            float a1 = pq  ? v1 : t1;
            float a2 = pq  ? t2 : v2;
            float a3 = pq  ? v3 : t3;
            // phase 2 (xor 2): swap bit1
            float u0 = __shfl_xor(a2, 2);
            float u1 = __shfl_xor(a3, 2);
            float u2 = __shfl_xor(a0, 2);
            float u3 = __shfl_xor(a1, 2);
            float w0 = pq2 ? u0 : a0;   // gate i
            float w1 = pq2 ? u1 : a1;   // gate f
            float w2 = pq2 ? a2 : u2;   // gate g
            float w3 = pq2 ? a3 : u3;   // gate o
            // this lane's (row, cell)
            int row = wr + mi * 16 + (lane >> 4) * 4 + (l15 & 3);
            int cl  = ((wc + ni * 16) >> 2) + (l15 >> 2);     // block-local cell
            float4 bi = *(const float4*)&bias_s[cl * 4];
            float iv = w0 + bi.x, fv = w1 + bi.y, gv = w2 + bi.z, ov = w3 + bi.w;
            long rloc = r0 + row;
            int nd = (int)(rloc >> 10), bb = (int)(rloc & 1023);
            int gcol = c0cell + cl;
            float c0v = 0.f;
            if (Cprev) {
                long ch = ((long)(offPrev + nd * 2) * 1024 + bb) * 256 + gcol;
                c0v = 0.5f * (Cprev[ch] + Cprev[ch + 262144]);
            }
            float cv = sigf(fv) * c0v + sigf(iv) * tanhf(gv);
            float hv = sigf(ov) * tanhf(cv);
            long orow = ((long)offCur * 1024 + rloc) * 256 + gcol;
            Cbuf[orow] = cv;
            Hbuf[orow] = f2bf(hv);
        }
    }
}

// ---------------------------------------------------------------------------
// Fused attention: logits + softmax + pooling. One block per (i, b).
// Writes pooled as bf16 (feeds the glds h0 GEMM).
// ---------------------------------------------------------------------------
__launch_bounds__(256)
__global__ void attn_fused(const float* __restrict__ E, const float* __restrict__ xextall,
                           const float* __restrict__ W_a, const u16* __restrict__ Hbuf,
                           u16* __restrict__ pooled, int level, int m, int off)
{
    const int blk = blockIdx.x;            // i*1024 + b
    const int i = blk >> 10, bb = blk & 1023;
    const int tid = threadIdx.x;
    const int ln = tid & 63, wv = tid >> 6;
    __shared__ float xs[64];
    __shared__ float raw[64];
    __shared__ float wsm[64];

    if (tid < 64) xs[tid] = xextall[((long)(off + i) * 1024 + bb) * 64 + tid];
    __syncthreads();

    const float wa = W_a[ln];
    for (int dd = wv; dd < m; dd += 4) {
        // decompose dd -> (source level lp, index q within it)
        int lp = 0, cum = 0;
        for (;;) { int sz = 1 << (level - lp); if (dd < cum + sz) break; cum += sz; lp++; }
        int sz = 1 << (level - lp);
        int q = dd - cum;
        long row = (long)((64 - (64 >> lp)) + i * sz + q) * 1024 + bb;
        float v = tanhf(E[row * 64 + ln] + xs[ln]) * wa;
#pragma unroll
        for (int s = 32; s; s >>= 1) v += __shfl_xor(v, s);
        if (ln == 0) raw[dd] = v;
    }
    __syncthreads();

    if (tid < 64) {
        float v = (tid < m) ? raw[tid] : -1e30f;
        float mx = v;
#pragma unroll
        for (int s = 32; s; s >>= 1) mx = fmaxf(mx, __shfl_xor(mx, s));
        float e = (tid < m) ? expf(v - mx) : 0.f;
        float sum = e;
#pragma unroll
        for (int s = 32; s; s >>= 1) sum += __shfl_xor(sum, s);
        wsm[tid] = e / sum;
    }
    __syncthreads();

    float accv = 0.f;
    int cum = 0;
    for (int lp = 0; lp < level; lp++) {
        int sz = 1 << (level - lp);
        int base = 64 - (64 >> lp);
        for (int q = 0; q < sz; q++) {
            long row = (long)(base + i * sz + q) * 1024 + bb;
            accv = fmaf(wsm[cum + q], b2f(Hbuf[row * 256 + tid]), accv);
        }
        cum += sz;
    }
    pooled[(long)blk * 256 + tid] = f2bf(accv);
}

// ---------------------------------------------------------------------------
// Output heads. One block per batch b; Hbuf root row is bf16.
// ---------------------------------------------------------------------------
__launch_bounds__(256)
__global__ void heads_kernel(const u16* __restrict__ Hbuf,
                             const float* __restrict__ W_c1, const float* __restrict__ b_c1,
                             const float* __restrict__ W_c2, const float* __restrict__ b_c2,
                             const float* __restrict__ W_c3, const float* __restrict__ b_c3,
                             const float* __restrict__ W_d1, const float* __restrict__ b_d1,
                             const float* __restrict__ W_d2, const float* __restrict__ b_d2,
                             const float* __restrict__ W_d3, const float* __restrict__ b_d3,
                             float* __restrict__ out)
{
    const int bb = blockIdx.x, tid = threadIdx.x;
    __shared__ float root[256];
    __shared__ float t1[128];
    __shared__ float t2[128];
    __shared__ float red[256];
    root[tid] = b2f(Hbuf[((long)62 * 1024 + bb) * 256 + tid]);
    __syncthreads();
    for (int head = 0; head < 2; head++) {
        const float* w1  = head ? W_d1 : W_c1;
        const float* bi1 = head ? b_d1 : b_c1;
        const float* w2  = head ? W_d2 : W_c2;
        const float* bi2 = head ? b_d2 : b_c2;
        const float* w3  = head ? W_d3 : W_c3;
        const float* bi3 = head ? b_d3 : b_c3;
        if (tid < 128) {
            float s = bi1[tid];
            for (int k = 0; k < 256; k++) s = fmaf(root[k], w1[k * 128 + tid], s);
            t1[tid] = fmaxf(s, 0.f);
        }
        __syncthreads();
        if (tid < 128) {
            float s = bi2[tid];
            for (int k = 0; k < 128; k++) s = fmaf(t1[k], w2[k * 128 + tid], s);
            t2[tid] = fmaxf(s, 0.f);
        }
        __syncthreads();
        red[tid] = (tid < 128) ? t2[tid] * w3[tid] : 0.f;
        __syncthreads();
        for (int s = 128; s; s >>= 1) { if (tid < s) red[tid] += red[tid + s]; __syncthreads(); }
        if (tid == 0) out[head * 1024 + bb] = sigf(red[0] + bi3[0]);
        __syncthreads();
    }
}

// ---------------------------------------------------------------------------
extern "C" void kernel_launch(void* const* d_in, const int* in_sizes, int n_in,
                              void* d_out, int out_size, void* d_ws, size_t ws_size,
                              hipStream_t stream)
{
    (void)in_sizes; (void)n_in; (void)out_size;
    const float* op       = (const float*)d_in[0];
    const float* feat     = (const float*)d_in[1];
    const float* cond1    = (const float*)d_in[2];
    const float* cond2    = (const float*)d_in[3];
    const float* bitmap   = (const float*)d_in[4];
    const float* has_cond = (const float*)d_in[5];
    const float* W_op     = (const float*)d_in[6];
    const float* b_op     = (const float*)d_in[7];
    const float* W_feat   = (const float*)d_in[8];
    const float* b_feat   = (const float*)d_in[9];
    const float* W_pred   = (const float*)d_in[10];
    const float* b_pred   = (const float*)d_in[11];
    const float* W_bm     = (const float*)d_in[12];
    const float* b_bm     = (const float*)d_in[13];
    const float* W_ih     = (const float*)d_in[14];
    const float* b_ih     = (const float*)d_in[15];
    const float* W_hh     = (const float*)d_in[16];
    const float* b_hh     = (const float*)d_in[17];
    const float* W_wh     = (const float*)d_in[18];
    const float* W_ext    = (const float*)d_in[19];
    const float* W_a      = (const float*)d_in[20];
    const float* W_ht     = (const float*)d_in[21];
    const float* b_ht     = (const float*)d_in[22];
    const float* W_c1     = (const float*)d_in[23];
    const float* b_c1     = (const float*)d_in[24];
    const float* W_c2     = (const float*)d_in[25];
    const float* b_c2     = (const float*)d_in[26];
    const float* W_c3     = (const float*)d_in[27];
    const float* b_c3     = (const float*)d_in[28];
    const float* W_d1     = (const float*)d_in[29];
    const float* b_d1     = (const float*)d_in[30];
    const float* W_d2     = (const float*)d_in[31];
    const float* b_d2     = (const float*)d_in[32];
    const float* W_d3     = (const float*)d_in[33];
    const float* b_d3     = (const float*)d_in[34];
    float* out = (float*)d_out;

    // workspace layout, node-major rows: row = node_global*1024 + b
    char* p = (char*)d_ws;
    auto alloc = [&](size_t bytes) -> char* {
        char* r = p; p += (bytes + 255) & ~(size_t)255; return r;
    };
    u16*   xall    = (u16*)  alloc((size_t)64512 * 640 * 2);   // bf16 x, all 63 nodes
    float* xextall = (float*)alloc((size_t)64512 * 64 * 4);    // x @ W_ext
    u16*   Hbuf    = (u16*)  alloc((size_t)64512 * 256 * 2);   // hiddens (bf16)
    float* Cbuf    = (float*)alloc((size_t)64512 * 256 * 4);   // cells (f32)
    float* Ebuf    = (float*)alloc((size_t)62 * 1024 * 64 * 4);// H @ W_wh
    u16*   pooled  = (u16*)  alloc((size_t)16384 * 256 * 2);   // bf16 pooled
    u16*   h0      = (u16*)  alloc((size_t)16384 * 256 * 2);
    u16*   Wt_op   = (u16*)  alloc((size_t)128 * 32 * 2);
    u16*   Wt_feat = (u16*)  alloc((size_t)128 * 64 * 2);
    u16*   Wt_pred = (u16*)  alloc((size_t)128 * 256 * 2);
    u16*   Wt_bm   = (u16*)  alloc((size_t)128 * 1024 * 2);
    u16*   Wt_g    = (u16*)  alloc((size_t)1024 * 896 * 2);    // interleaved rows
    u16*   Wt_wh   = (u16*)  alloc((size_t)64 * 256 * 2);
    u16*   Wt_ext  = (u16*)  alloc((size_t)64 * 640 * 2);
    u16*   Wt_ht   = (u16*)  alloc((size_t)256 * 256 * 2);
    if (ws_size < (size_t)(p - (char*)d_ws)) return;

    // ---- weight prep (bf16, [N][K] with K zero-padded to x32)
    prep_w<<<16,  256, 0, stream>>>(W_op,   Wt_op,   32,   128, 32);
    prep_w<<<32,  256, 0, stream>>>(W_feat, Wt_feat, 64,   128, 64);
    prep_w<<<128, 256, 0, stream>>>(W_pred, Wt_pred, 256,  128, 256);
    prep_w<<<512, 256, 0, stream>>>(W_bm,   Wt_bm,   1000, 128, 1024);
    prep_w<<<64,  256, 0, stream>>>(W_wh,   Wt_wh,   256,  64,  256);
    prep_w<<<160, 256, 0, stream>>>(W_ext,  Wt_ext,  640,  64,  640);
    prep_w<<<256, 256, 0, stream>>>(W_ht,   Wt_ht,   256,  256, 256);
    prep_g<<<3584,256, 0, stream>>>(W_ih, W_hh, Wt_g);

    // ---- x projections for ALL 63 nodes at once (M = 64512 = 504*128)
    gemm_bf16<true,128><<<dim3(504,1), 256, 0, stream>>>(op,     Wt_op,   (void*)(xall + 0),   b_op,   nullptr,  32,   32,   32,   640, 1, 0, 1);
    gemm_bf16<true,128><<<dim3(504,1), 256, 0, stream>>>(feat,   Wt_feat, (void*)(xall + 128), b_feat, nullptr,  64,   64,   64,   640, 1, 0, 1);
    gemm_bf16<true,128><<<dim3(504,1), 256, 0, stream>>>(cond1,  Wt_pred, (void*)(xall + 256), b_pred, nullptr,  256,  256,  256,  640, 1, 0, 1);
    gemm_bf16<true,128><<<dim3(504,1), 256, 0, stream>>>(cond2,  Wt_pred, (void*)(xall + 384), b_pred, nullptr,  256,  256,  256,  640, 1, 0, 1);
    gemm_bf16<true,128><<<dim3(504,1), 256, 0, stream>>>(bitmap, Wt_bm,   (void*)(xall + 512), b_bm,   has_cond, 1000, 1024, 1000, 640, 1, 0, 1);
    // xext for all nodes
    gemm_glds64<<<dim3(504,1), 256, 0, stream>>>(xall, Wt_ext, (void*)xextall, nullptr, 640, 640, 64, 0, 0, 0);

    for (int l = 0; l < 6; l++) {
        const int n   = 32 >> l;
        const int off = 64 - (64 >> l);     // OFFSETS[l] = global node base
        const int M   = n * 1024;
        const int m   = (2 << l) - 2;

        if (l > 0) {
            attn_fused<<<M, 256, 0, stream>>>(Ebuf, xextall, W_a, Hbuf, pooled, l, m, off);
            gemm_glds64<<<dim3(M/128, 4), 256, 0, stream>>>(pooled, Wt_ht, (void*)h0, b_ht, 256, 256, 256, 1, 1, 1);
        }

        const int Ktot    = l ? 896 : 640;
        const int offPrev = l ? (64 - (64 >> (l - 1))) : 0;
        gates_glds<<<(M/128) * 4, 512, 0, stream>>>(xall + (size_t)off * 1024 * 640, h0, Wt_g,
                                                    b_ih, b_hh, l ? Cbuf : nullptr,
                                                    Hbuf, Cbuf, off, offPrev, Ktot);

        if (l < 5) {
            gemm_glds64<<<dim3(M/128, 1), 256, 0, stream>>>(Hbuf + (size_t)off * 1024 * 256, Wt_wh,
                                                            (void*)(Ebuf + (size_t)off * 1024 * 64),
                                                            nullptr, 256, 256, 64, 0, 0, 0);
        }
    }

    heads_kernel<<<1024, 256, 0, stream>>>(Hbuf, W_c1, b_c1, W_c2, b_c2, W_c3, b_c3,
                                           W_d1, b_d1, W_d2, b_d2, W_d3, b_d3, out);
}